// Round 4
// baseline (4487.130 us; speedup 1.0000x reference)
//
#include <hip/hip_runtime.h>
#include <hip/hip_bf16.h>

// Causal self-attention fwd, B=2, H=16, S=2048, D=64.
// Inputs fp32 (round-1 NaN -> round-2 finite flip under sniff).
// Outputs fp32 (harness spec: output dtype = reference output dtype = fp32;
// rounds 2/3 identical absmax across different kernels => I/O misread, and
// bf16-written-to-fp32-read scrambling predicts the observed ~4.5 error).
// d_out = [out (B*H*S*D)] ++ [attention (B*H*S*S)], both fp32.

#define B_ 2
#define H_ 16
#define S_ 2048
#define D_ 64

typedef unsigned short u16;
typedef unsigned int   u32;

__device__ __forceinline__ float bf2f(u16 h) {
    union { u32 u; float f; } x; x.u = ((u32)h) << 16; return x.f;
}

__global__ __launch_bounds__(256)
void attn_row_kernel(const void* __restrict__ Qv, const void* __restrict__ Kv,
                     const void* __restrict__ Vv, const int* __restrict__ maskp,
                     float* __restrict__ out, float* __restrict__ att)
{
    const int tid = threadIdx.x;
    const int row = blockIdx.x;            // row = bh*S + q
    const int bh  = row >> 11;             // / S_
    const int q   = row & (S_ - 1);
    const int causal = maskp[0];
    const int kmax = causal ? q : (S_ - 1);

    __shared__ float sQ[D_];
    __shared__ float sS[S_];       // score row (8 KB)
    __shared__ float sRed[256];
    __shared__ int   sFlag;

    const size_t base = (size_t)bh * S_ * D_;

    // ---- input dtype sniff (insurance): fp32 misread as bf16 shows huge
    // exponent fields in the low halves; genuine bf16 N(0,1) never does. ----
    if (tid == 0) {
        const u16* q16 = (const u16*)Qv;
        int hits = 0;
        for (int i = 0; i < 128; ++i) {
            u32 e = ((u32)q16[i] >> 7) & 0xFFu;
            hits += (e >= 0x8Fu) ? 1 : 0;
        }
        sFlag = (hits >= 4) ? 1 : 0;
    }
    __syncthreads();
    const bool isf32 = (sFlag != 0);

    // ---- load Q row, pre-scaled by 1/sqrt(64) ----
    if (tid < D_) {
        float qv = isf32 ? ((const float*)Qv)[base + (size_t)q * D_ + tid]
                         : bf2f(((const u16*)Qv)[base + (size_t)q * D_ + tid]);
        sQ[tid] = qv * 0.125f;
    }
    __syncthreads();

    // ---- scores: s_j = (Q[q] . K[j]) / 8, masked to -inf ----
    if (isf32) {
        const float* Kf = (const float*)Kv + base;
        for (int j = tid; j < S_; j += 256) {
            float s = -INFINITY;
            if (j <= kmax) {
                const float4* kr = reinterpret_cast<const float4*>(Kf + (size_t)j * D_);
                float acc = 0.f;
                #pragma unroll
                for (int c = 0; c < 16; ++c) {
                    float4 p = kr[c];
                    acc += sQ[c*4+0] * p.x;
                    acc += sQ[c*4+1] * p.y;
                    acc += sQ[c*4+2] * p.z;
                    acc += sQ[c*4+3] * p.w;
                }
                s = acc;
            }
            sS[j] = s;
        }
    } else {
        const u16* Kh = (const u16*)Kv + base;
        for (int j = tid; j < S_; j += 256) {
            float s = -INFINITY;
            if (j <= kmax) {
                float acc = 0.f;
                const u16* kr = Kh + (size_t)j * D_;
                #pragma unroll
                for (int c = 0; c < D_; ++c) acc += sQ[c] * bf2f(kr[c]);
                s = acc;
            }
            sS[j] = s;
        }
    }
    __syncthreads();

    // ---- block max via LDS tree ----
    {
        float lm = -INFINITY;
        for (int j = tid; j < S_; j += 256) lm = fmaxf(lm, sS[j]);
        sRed[tid] = lm;
    }
    __syncthreads();
    #pragma unroll
    for (int s = 128; s > 0; s >>= 1) {
        if (tid < s) sRed[tid] = fmaxf(sRed[tid], sRed[tid + s]);
        __syncthreads();
    }
    const float m = sRed[0];
    __syncthreads();               // safe to reuse sRed

    // ---- exp (in place) + block sum via LDS tree ----
    {
        float ls = 0.f;
        for (int j = tid; j <= kmax; j += 256) {
            float e = expf(sS[j] - m);
            sS[j] = e;
            ls += e;
        }
        sRed[tid] = ls;
    }
    __syncthreads();
    #pragma unroll
    for (int s = 128; s > 0; s >>= 1) {
        if (tid < s) sRed[tid] = sRed[tid] + sRed[tid + s];
        __syncthreads();
    }
    const float l   = sRed[0];
    const float inv = 1.f / l;
    __syncthreads();               // safe to reuse sRed

    // ---- normalize + write attention row (fp32, float4 stores) ----
    float* attRow = att + (size_t)row * S_;
    {
        const int j0 = tid * 8;    // 256 * 8 == 2048
        float p[8];
        #pragma unroll
        for (int c = 0; c < 8; ++c) {
            int j = j0 + c;
            p[c] = (j <= kmax) ? sS[j] * inv : 0.f;
            sS[j] = p[c];
        }
        float4* attRow4 = reinterpret_cast<float4*>(attRow + j0);
        attRow4[0] = make_float4(p[0], p[1], p[2], p[3]);
        attRow4[1] = make_float4(p[4], p[5], p[6], p[7]);
    }
    __syncthreads();

    // ---- out[q][d] = sum_j p_j * V[j][d], 4-way j-split + LDS reduce ----
    const int d = tid & 63;
    const int g = tid >> 6;
    float acc = 0.f;
    if (isf32) {
        const float* Vf = (const float*)Vv + base;
        for (int j = g; j <= kmax; j += 4) acc += sS[j] * Vf[(size_t)j * D_ + d];
    } else {
        const u16* Vh = (const u16*)Vv + base;
        for (int j = g; j <= kmax; j += 4) acc += sS[j] * bf2f(Vh[(size_t)j * D_ + d]);
    }
    sRed[tid] = acc;
    __syncthreads();
    if (tid < D_) {
        float o = sRed[tid] + sRed[64 + tid] + sRed[128 + tid] + sRed[192 + tid];
        out[(size_t)row * D_ + tid] = o;
    }
}

extern "C" void kernel_launch(void* const* d_in, const int* in_sizes, int n_in,
                              void* d_out, int out_size, void* d_ws, size_t ws_size,
                              hipStream_t stream) {
    const void* Q = d_in[0];
    const void* K = d_in[1];
    const void* V = d_in[2];
    const int* mask = (const int*)d_in[3];

    float* out = (float*)d_out;                              // B*H*S*D floats
    float* att = out + (size_t)B_ * H_ * S_ * D_;            // B*H*S*S floats

    const int nrows = B_ * H_ * S_;                          // 65536 blocks
    attn_row_kernel<<<nrows, 256, 0, stream>>>(Q, K, V, mask, out, att);
}